// Round 1
// baseline (3002.561 us; speedup 1.0000x reference)
//
#include <hip/hip_runtime.h>
#include <hip/hip_bf16.h>

typedef unsigned short u16;
typedef unsigned int u32;
typedef __attribute__((ext_vector_type(8))) __bf16 bf16x8;
typedef __attribute__((ext_vector_type(4))) float floatx4;
typedef __attribute__((ext_vector_type(4))) u32 u32x4;

#define B_DIM 4096
#define H_DIM 4096
#define V_DIM 4096
#define KX 8192   // V+H

// ---------- helpers ----------
__device__ __forceinline__ u16 f32_to_bf16(float f) {
    u32 u = __builtin_bit_cast(u32, f);
    u += 0x7fffu + ((u >> 16) & 1u);   // round-to-nearest-even
    return (u16)(u >> 16);
}

__device__ __forceinline__ u32 pack2(float a, float b) {
    return (u32)f32_to_bf16(a) | ((u32)f32_to_bf16(b) << 16);
}

__device__ __forceinline__ float sigmoid_f(float x) {
    return 1.0f / (1.0f + __expf(-x));
}

__device__ __forceinline__ float tanh_f(float x) {
    float e = __expf(-2.0f * fabsf(x));
    float t = (1.0f - e) / (1.0f + e);
    return x >= 0.0f ? t : -t;
}

// async global->LDS, 16B per lane; LDS dest = wave-uniform base + lane*16
__device__ __forceinline__ void gld_lds16(const u16* g, u16* l) {
    __builtin_amdgcn_global_load_lds(
        (const __attribute__((address_space(1))) u32*)g,
        (__attribute__((address_space(3))) u32*)l, 16, 0, 0);
}

// ---------- conversion kernels ----------
__global__ __launch_bounds__(256) void cvt_f32_bf16(const float* __restrict__ src,
                                                    u16* __restrict__ dst, int n4) {
    int t = blockIdx.x * 256 + threadIdx.x;
    if (t < n4) {
        float4 f = ((const float4*)src)[t];
        uint2 u;
        u.x = pack2(f.x, f.y);
        u.y = pack2(f.z, f.w);
        ((uint2*)dst)[t] = u;
    }
}

// build xh = concat(x, h) as bf16, [4096][8192]
__global__ __launch_bounds__(256) void build_xh(const float* __restrict__ x,
                                                const float* __restrict__ h,
                                                u16* __restrict__ xh) {
    size_t t = (size_t)blockIdx.x * 256 + threadIdx.x;   // one thread per 4 elems
    size_t idx = t * 4;
    size_t row = idx >> 13;          // /8192
    int col = (int)(idx & 8191);
    const float* s = (col < V_DIM) ? (x + row * V_DIM + col)
                                   : (h + row * H_DIM + (col - V_DIM));
    float4 f = *(const float4*)s;
    uint2 u;
    u.x = pack2(f.x, f.y);
    u.y = pack2(f.z, f.w);
    *(uint2*)(xh + idx) = u;
}

// ---------- fused 4-gate GEMM + LSTM elementwise ----------
// Tile: BM=128 (batch) x BN=64 (hidden) per gate, BK=64, 256 threads (4 waves, 2x2)
#define GBM 128
#define GBN 64
#define GBK 64

__global__ __launch_bounds__(256) void gate_gemm(
    const u16* __restrict__ xh,     // [4096][8192] bf16
    const u16* __restrict__ Wg,     // [4][4096][8192] bf16 (f,i,c,o)
    const float* __restrict__ bias_f, const float* __restrict__ bias_i,
    const float* __restrict__ bias_c, const float* __restrict__ bias_o,
    const float* __restrict__ c_in, // [4096][4096] f32
    u16* __restrict__ hnew)         // [4096][4096] bf16
{
    const int K = KX;
    int m0 = blockIdx.x * GBM;
    int n0 = blockIdx.y * GBN;
    int tid = threadIdx.x;
    int w = tid >> 6, lane = tid & 63;
    int wm = w >> 1, wn = w & 1;

    __shared__ __attribute__((aligned(16))) u16 As[GBM * GBK];      // 16 KB
    __shared__ __attribute__((aligned(16))) u16 Bs[4 * GBN * GBK];  // 32 KB

    floatx4 acc[4][4][2] = {};   // [gate][mi][ni]

    int arow = lane >> 3;           // 0..7 within an 8-row chunk
    int acol = (lane & 7) * 8;      // 8 bf16 = 16B per lane
    int col_l = lane & 15, quad = lane >> 4;

    for (int kt = 0; kt < K; kt += GBK) {
        // stage A: 16 chunks of 8 rows, 4 per wave
#pragma unroll
        for (int it = 0; it < 4; ++it) {
            int ci = it * 4 + w;
            const u16* g = xh + (size_t)(m0 + ci * 8 + arow) * K + kt + acol;
            gld_lds16(g, As + ci * 512 + lane * 8);
        }
        // stage B: per gate 8 chunks of 8 rows, 2 iters/wave/gate
#pragma unroll
        for (int g4 = 0; g4 < 4; ++g4) {
#pragma unroll
            for (int jt = 0; jt < 2; ++jt) {
                int ci = jt * 4 + w;
                const u16* gp = Wg + (size_t)g4 * H_DIM * KX
                               + (size_t)(n0 + ci * 8 + arow) * K + kt + acol;
                gld_lds16(gp, Bs + g4 * 4096 + ci * 512 + lane * 8);
            }
        }
        __syncthreads();

#pragma unroll
        for (int kk = 0; kk < 2; ++kk) {
            bf16x8 a_frag[4];
#pragma unroll
            for (int mi = 0; mi < 4; ++mi) {
                u32x4 av = *(const u32x4*)(As + (wm * 64 + mi * 16 + col_l) * GBK
                                           + kk * 32 + quad * 8);
                a_frag[mi] = __builtin_bit_cast(bf16x8, av);
            }
#pragma unroll
            for (int g4 = 0; g4 < 4; ++g4) {
#pragma unroll
                for (int ni = 0; ni < 2; ++ni) {
                    u32x4 bv = *(const u32x4*)(Bs + g4 * 4096
                                               + (wn * 32 + ni * 16 + col_l) * GBK
                                               + kk * 32 + quad * 8);
                    bf16x8 b_frag = __builtin_bit_cast(bf16x8, bv);
#pragma unroll
                    for (int mi = 0; mi < 4; ++mi)
                        acc[g4][mi][ni] = __builtin_amdgcn_mfma_f32_16x16x32_bf16(
                            a_frag[mi], b_frag, acc[g4][mi][ni], 0, 0, 0);
                }
            }
        }
        __syncthreads();
    }

    // epilogue: bias + activations + LSTM combine; C/D layout: col=lane&15, row=quad*4+r
#pragma unroll
    for (int ni = 0; ni < 2; ++ni) {
        int col = n0 + wn * 32 + ni * 16 + col_l;
        float bfv = bias_f[col], biv = bias_i[col];
        float bcv = bias_c[col], bov = bias_o[col];
#pragma unroll
        for (int mi = 0; mi < 4; ++mi) {
#pragma unroll
            for (int r = 0; r < 4; ++r) {
                int row = m0 + wm * 64 + mi * 16 + quad * 4 + r;
                size_t off = (size_t)row * H_DIM + col;
                float fg = sigmoid_f(acc[0][mi][ni][r] + bfv);
                float ig = sigmoid_f(acc[1][mi][ni][r] + biv);
                float cd = tanh_f(acc[2][mi][ni][r] + bcv);
                float og = sigmoid_f(acc[3][mi][ni][r] + bov);
                float cn = c_in[off] * fg + cd * ig;
                hnew[off] = f32_to_bf16(tanh_f(cn) * og);
            }
        }
    }
}

// ---------- out GEMM: logits = hnew @ Wout^T + bout (m97-style 128x128) ----------
__global__ __launch_bounds__(256) void out_gemm(
    const u16* __restrict__ A,   // hnew [4096][4096] bf16
    const u16* __restrict__ Bw,  // Wout [4096][4096] bf16 ([N][K])
    const float* __restrict__ bout,
    float* __restrict__ out)     // logits [4096][4096] f32
{
    const int K = H_DIM;
    int m0 = blockIdx.x * 128, n0 = blockIdx.y * 128;
    int tid = threadIdx.x;
    int w = tid >> 6, lane = tid & 63;
    int wm = w >> 1, wn = w & 1;

    __shared__ __attribute__((aligned(16))) u16 As[128 * 64];
    __shared__ __attribute__((aligned(16))) u16 Bs[128 * 64];

    floatx4 acc[4][4] = {};
    int arow = lane >> 3;
    int acol = (lane & 7) * 8;
    int col_l = lane & 15, quad = lane >> 4;

    for (int kt = 0; kt < K; kt += 64) {
#pragma unroll
        for (int it = 0; it < 4; ++it) {
            int ci = it * 4 + w;
            gld_lds16(A  + (size_t)(m0 + ci * 8 + arow) * K + kt + acol,
                      As + ci * 512 + lane * 8);
            gld_lds16(Bw + (size_t)(n0 + ci * 8 + arow) * K + kt + acol,
                      Bs + ci * 512 + lane * 8);
        }
        __syncthreads();
#pragma unroll
        for (int kk = 0; kk < 2; ++kk) {
            bf16x8 a_frag[4], b_frag[4];
#pragma unroll
            for (int mi = 0; mi < 4; ++mi) {
                u32x4 av = *(const u32x4*)(As + (wm * 64 + mi * 16 + col_l) * 64
                                           + kk * 32 + quad * 8);
                a_frag[mi] = __builtin_bit_cast(bf16x8, av);
            }
#pragma unroll
            for (int ni = 0; ni < 4; ++ni) {
                u32x4 bv = *(const u32x4*)(Bs + (wn * 64 + ni * 16 + col_l) * 64
                                           + kk * 32 + quad * 8);
                b_frag[ni] = __builtin_bit_cast(bf16x8, bv);
            }
#pragma unroll
            for (int mi = 0; mi < 4; ++mi)
#pragma unroll
                for (int ni = 0; ni < 4; ++ni)
                    acc[mi][ni] = __builtin_amdgcn_mfma_f32_16x16x32_bf16(
                        a_frag[mi], b_frag[ni], acc[mi][ni], 0, 0, 0);
        }
        __syncthreads();
    }

#pragma unroll
    for (int ni = 0; ni < 4; ++ni) {
        int col = n0 + wn * 64 + ni * 16 + col_l;
        float bv = bout[col];
#pragma unroll
        for (int mi = 0; mi < 4; ++mi) {
#pragma unroll
            for (int r = 0; r < 4; ++r) {
                int row = m0 + wm * 64 + mi * 16 + quad * 4 + r;
                out[(size_t)row * V_DIM + col] = acc[mi][ni][r] + bv;
            }
        }
    }
}

// ---------- row softmax, in place on d_out ----------
__global__ __launch_bounds__(256) void softmax_rows(float* __restrict__ out) {
    float4* p = (float4*)(out + (size_t)blockIdx.x * V_DIM);
    int tid = threadIdx.x;
    int w = tid >> 6, lane = tid & 63;
    float4 v[4];
    float mx = -3.4e38f;
#pragma unroll
    for (int i = 0; i < 4; ++i) {
        v[i] = p[tid + i * 256];
        mx = fmaxf(mx, fmaxf(fmaxf(v[i].x, v[i].y), fmaxf(v[i].z, v[i].w)));
    }
#pragma unroll
    for (int off = 32; off > 0; off >>= 1) mx = fmaxf(mx, __shfl_xor(mx, off));
    __shared__ float red[4];
    __shared__ float red2[4];
    if (lane == 0) red[w] = mx;
    __syncthreads();
    mx = fmaxf(fmaxf(red[0], red[1]), fmaxf(red[2], red[3]));
    float s = 0.f;
#pragma unroll
    for (int i = 0; i < 4; ++i) {
        v[i].x = __expf(v[i].x - mx); v[i].y = __expf(v[i].y - mx);
        v[i].z = __expf(v[i].z - mx); v[i].w = __expf(v[i].w - mx);
        s += v[i].x + v[i].y + v[i].z + v[i].w;
    }
#pragma unroll
    for (int off = 32; off > 0; off >>= 1) s += __shfl_xor(s, off);
    if (lane == 0) red2[w] = s;
    __syncthreads();
    s = red2[0] + red2[1] + red2[2] + red2[3];
    float inv = 1.0f / s;
#pragma unroll
    for (int i = 0; i < 4; ++i) {
        v[i].x *= inv; v[i].y *= inv; v[i].z *= inv; v[i].w *= inv;
        p[tid + i * 256] = v[i];
    }
}

// ---------- launch ----------
extern "C" void kernel_launch(void* const* d_in, const int* in_sizes, int n_in,
                              void* d_out, int out_size, void* d_ws, size_t ws_size,
                              hipStream_t stream) {
    const float* x    = (const float*)d_in[0];
    const float* h    = (const float*)d_in[1];
    const float* c    = (const float*)d_in[2];
    const float* Wf   = (const float*)d_in[3];
    const float* bf_  = (const float*)d_in[4];
    const float* Wi   = (const float*)d_in[5];
    const float* bi   = (const float*)d_in[6];
    const float* Wc   = (const float*)d_in[7];
    const float* bc   = (const float*)d_in[8];
    const float* Wo   = (const float*)d_in[9];
    const float* bo   = (const float*)d_in[10];
    const float* Wout = (const float*)d_in[11];
    const float* bout = (const float*)d_in[12];

    const size_t XH_ELEMS = (size_t)B_DIM * KX;        // 33,554,432
    const size_t W_ELEMS  = (size_t)H_DIM * KX;        // 33,554,432 per gate
    const size_t HH_ELEMS = (size_t)B_DIM * H_DIM;     // 16,777,216

    // ws layout (bf16/u16 elements): xh | Wg[4] | WoutB | hnew  = 384 MiB total
    u16* xh    = (u16*)d_ws;
    u16* Wg    = xh + XH_ELEMS;
    u16* WoutB = Wg + 4 * W_ELEMS;
    u16* hnew  = WoutB + HH_ELEMS;
    size_t needed = (XH_ELEMS + 4 * W_ELEMS + 2 * HH_ELEMS) * sizeof(u16);
    if (ws_size < needed) return;   // workspace too small: bail rather than corrupt

    float* logits = (float*)d_out;

    // conversions (fp32 -> bf16)
    build_xh<<<(int)(XH_ELEMS / 4 / 256), 256, 0, stream>>>(x, h, xh);
    int w4 = (int)(W_ELEMS / 4);
    cvt_f32_bf16<<<w4 / 256, 256, 0, stream>>>(Wf, Wg + 0 * W_ELEMS, w4);
    cvt_f32_bf16<<<w4 / 256, 256, 0, stream>>>(Wi, Wg + 1 * W_ELEMS, w4);
    cvt_f32_bf16<<<w4 / 256, 256, 0, stream>>>(Wc, Wg + 2 * W_ELEMS, w4);
    cvt_f32_bf16<<<w4 / 256, 256, 0, stream>>>(Wo, Wg + 3 * W_ELEMS, w4);
    int wo4 = (int)(HH_ELEMS / 4);
    cvt_f32_bf16<<<wo4 / 256, 256, 0, stream>>>(Wout, WoutB, wo4);

    // fused 4-gate GEMM + LSTM elementwise -> hnew (bf16)
    gate_gemm<<<dim3(B_DIM / GBM, H_DIM / GBN), 256, 0, stream>>>(
        xh, Wg, bf_, bi, bc, bo, c, hnew);

    // logits = hnew @ Wout^T + bout -> d_out (fp32)
    out_gemm<<<dim3(B_DIM / 128, V_DIM / 128), 256, 0, stream>>>(
        hnew, WoutB, bout, logits);

    // softmax rows in place
    softmax_rows<<<B_DIM, 256, 0, stream>>>(logits);
}

// Round 2
// 2819.733 us; speedup vs baseline: 1.0648x; 1.0648x over previous
//
#include <hip/hip_runtime.h>
#include <hip/hip_bf16.h>

typedef unsigned short u16;
typedef unsigned int u32;
typedef __attribute__((ext_vector_type(8))) __bf16 bf16x8;
typedef __attribute__((ext_vector_type(4))) float floatx4;
typedef __attribute__((ext_vector_type(4))) u32 u32x4;

#define B_DIM 4096
#define H_DIM 4096
#define V_DIM 4096
#define KX 8192   // V+H

// ---------- helpers ----------
__device__ __forceinline__ u16 f32_to_bf16(float f) {
    u32 u = __builtin_bit_cast(u32, f);
    u += 0x7fffu + ((u >> 16) & 1u);   // round-to-nearest-even
    return (u16)(u >> 16);
}

__device__ __forceinline__ u32 pack2(float a, float b) {
    return (u32)f32_to_bf16(a) | ((u32)f32_to_bf16(b) << 16);
}

__device__ __forceinline__ float sigmoid_f(float x) {
    return 1.0f / (1.0f + __expf(-x));
}

__device__ __forceinline__ float tanh_f(float x) {
    float e = __expf(-2.0f * fabsf(x));
    float t = (1.0f - e) / (1.0f + e);
    return x >= 0.0f ? t : -t;
}

// async global->LDS, 16B per lane; LDS dest = wave-uniform base + lane*16
__device__ __forceinline__ void gld_lds16(const u16* g, u16* l) {
    __builtin_amdgcn_global_load_lds(
        (const __attribute__((address_space(1))) u32*)g,
        (__attribute__((address_space(3))) u32*)l, 16, 0, 0);
}

// ---------- conversion kernels ----------
__global__ __launch_bounds__(256) void cvt_f32_bf16(const float* __restrict__ src,
                                                    u16* __restrict__ dst, int n4) {
    int t = blockIdx.x * 256 + threadIdx.x;
    if (t < n4) {
        float4 f = ((const float4*)src)[t];
        uint2 u;
        u.x = pack2(f.x, f.y);
        u.y = pack2(f.z, f.w);
        ((uint2*)dst)[t] = u;
    }
}

// build xh = concat(x, h) as bf16, [4096][8192]
__global__ __launch_bounds__(256) void build_xh(const float* __restrict__ x,
                                                const float* __restrict__ h,
                                                u16* __restrict__ xh) {
    size_t t = (size_t)blockIdx.x * 256 + threadIdx.x;   // one thread per 4 elems
    size_t idx = t * 4;
    size_t row = idx >> 13;          // /8192
    int col = (int)(idx & 8191);
    const float* s = (col < V_DIM) ? (x + row * V_DIM + col)
                                   : (h + row * H_DIM + (col - V_DIM));
    float4 f = *(const float4*)s;
    uint2 u;
    u.x = pack2(f.x, f.y);
    u.y = pack2(f.z, f.w);
    *(uint2*)(xh + idx) = u;
}

// ---------- fused 4-gate GEMM + LSTM elementwise ----------
// Tile: BM=128 (batch) x BN=64 (hidden) per gate, BK=64, 256 threads (4 waves, 2x2)
// LDS layout XOR-swizzled: logical 16B-chunk c of row r lives at slot (c ^ (r&7)).
// Staging keeps the wave-uniform global_load_lds dst (lane*16) and permutes the
// global SOURCE column instead (coalescing preserved: same 8x128B segments).
#define GBM 128
#define GBN 64
#define GBK 64

__global__ __launch_bounds__(256) void gate_gemm(
    const u16* __restrict__ xh,     // [4096][8192] bf16
    const u16* __restrict__ Wg,     // [4][4096][8192] bf16 (f,i,c,o)
    const float* __restrict__ bias_f, const float* __restrict__ bias_i,
    const float* __restrict__ bias_c, const float* __restrict__ bias_o,
    const float* __restrict__ c_in, // [4096][4096] f32
    u16* __restrict__ hnew)         // [4096][4096] bf16
{
    const int K = KX;
    int m0 = blockIdx.x * GBM;
    int n0 = blockIdx.y * GBN;
    int tid = threadIdx.x;
    int w = tid >> 6, lane = tid & 63;
    int wm = w >> 1, wn = w & 1;

    __shared__ __attribute__((aligned(16))) u16 As[GBM * GBK];      // 16 KB
    __shared__ __attribute__((aligned(16))) u16 Bs[4 * GBN * GBK];  // 32 KB

    floatx4 acc[4][4][2] = {};   // [gate][mi][ni]

    int arow = lane >> 3;                       // 0..7 row within 8-row chunk
    int acol = ((lane & 7) ^ arow) * 8;         // XOR-swizzled source column chunk
    int col_l = lane & 15, quad = lane >> 4;
    int swz = col_l & 7;                        // r&7 for fragment rows

    for (int kt = 0; kt < K; kt += GBK) {
        // stage A: 16 chunks of 8 rows, 4 per wave
#pragma unroll
        for (int it = 0; it < 4; ++it) {
            int ci = it * 4 + w;
            const u16* g = xh + (size_t)(m0 + ci * 8 + arow) * K + kt + acol;
            gld_lds16(g, As + ci * 512 + lane * 8);
        }
        // stage B: per gate 8 chunks of 8 rows, 2 iters/wave/gate
#pragma unroll
        for (int g4 = 0; g4 < 4; ++g4) {
#pragma unroll
            for (int jt = 0; jt < 2; ++jt) {
                int ci = jt * 4 + w;
                const u16* gp = Wg + (size_t)g4 * H_DIM * KX
                               + (size_t)(n0 + ci * 8 + arow) * K + kt + acol;
                gld_lds16(gp, Bs + g4 * 4096 + ci * 512 + lane * 8);
            }
        }
        __syncthreads();

#pragma unroll
        for (int kk = 0; kk < 2; ++kk) {
            bf16x8 a_frag[4];
#pragma unroll
            for (int mi = 0; mi < 4; ++mi) {
                u32x4 av = *(const u32x4*)(As + (wm * 64 + mi * 16 + col_l) * GBK
                                           + (((kk * 4 + quad) ^ swz) * 8));
                a_frag[mi] = __builtin_bit_cast(bf16x8, av);
            }
#pragma unroll
            for (int g4 = 0; g4 < 4; ++g4) {
#pragma unroll
                for (int ni = 0; ni < 2; ++ni) {
                    u32x4 bv = *(const u32x4*)(Bs + g4 * 4096
                                               + (wn * 32 + ni * 16 + col_l) * GBK
                                               + (((kk * 4 + quad) ^ swz) * 8));
                    bf16x8 b_frag = __builtin_bit_cast(bf16x8, bv);
#pragma unroll
                    for (int mi = 0; mi < 4; ++mi)
                        acc[g4][mi][ni] = __builtin_amdgcn_mfma_f32_16x16x32_bf16(
                            a_frag[mi], b_frag, acc[g4][mi][ni], 0, 0, 0);
                }
            }
        }
        __syncthreads();
    }

    // epilogue: bias + activations + LSTM combine; C/D layout: col=lane&15, row=quad*4+r
#pragma unroll
    for (int ni = 0; ni < 2; ++ni) {
        int col = n0 + wn * 32 + ni * 16 + col_l;
        float bfv = bias_f[col], biv = bias_i[col];
        float bcv = bias_c[col], bov = bias_o[col];
#pragma unroll
        for (int mi = 0; mi < 4; ++mi) {
#pragma unroll
            for (int r = 0; r < 4; ++r) {
                int row = m0 + wm * 64 + mi * 16 + quad * 4 + r;
                size_t off = (size_t)row * H_DIM + col;
                float fg = sigmoid_f(acc[0][mi][ni][r] + bfv);
                float ig = sigmoid_f(acc[1][mi][ni][r] + biv);
                float cd = tanh_f(acc[2][mi][ni][r] + bcv);
                float og = sigmoid_f(acc[3][mi][ni][r] + bov);
                float cn = c_in[off] * fg + cd * ig;
                hnew[off] = f32_to_bf16(tanh_f(cn) * og);
            }
        }
    }
}

// ---------- out GEMM: logits = hnew @ Wout^T + bout (m97-style 128x128) ----------
__global__ __launch_bounds__(256) void out_gemm(
    const u16* __restrict__ A,   // hnew [4096][4096] bf16
    const u16* __restrict__ Bw,  // Wout [4096][4096] bf16 ([N][K])
    const float* __restrict__ bout,
    float* __restrict__ out)     // logits [4096][4096] f32
{
    const int K = H_DIM;
    int m0 = blockIdx.x * 128, n0 = blockIdx.y * 128;
    int tid = threadIdx.x;
    int w = tid >> 6, lane = tid & 63;
    int wm = w >> 1, wn = w & 1;

    __shared__ __attribute__((aligned(16))) u16 As[128 * 64];
    __shared__ __attribute__((aligned(16))) u16 Bs[128 * 64];

    floatx4 acc[4][4] = {};
    int arow = lane >> 3;
    int acol = ((lane & 7) ^ arow) * 8;          // XOR-swizzled source column chunk
    int col_l = lane & 15, quad = lane >> 4;
    int swz = col_l & 7;

    for (int kt = 0; kt < K; kt += 64) {
#pragma unroll
        for (int it = 0; it < 4; ++it) {
            int ci = it * 4 + w;
            gld_lds16(A  + (size_t)(m0 + ci * 8 + arow) * K + kt + acol,
                      As + ci * 512 + lane * 8);
            gld_lds16(Bw + (size_t)(n0 + ci * 8 + arow) * K + kt + acol,
                      Bs + ci * 512 + lane * 8);
        }
        __syncthreads();
#pragma unroll
        for (int kk = 0; kk < 2; ++kk) {
            bf16x8 a_frag[4], b_frag[4];
#pragma unroll
            for (int mi = 0; mi < 4; ++mi) {
                u32x4 av = *(const u32x4*)(As + (wm * 64 + mi * 16 + col_l) * 64
                                           + (((kk * 4 + quad) ^ swz) * 8));
                a_frag[mi] = __builtin_bit_cast(bf16x8, av);
            }
#pragma unroll
            for (int ni = 0; ni < 4; ++ni) {
                u32x4 bv = *(const u32x4*)(Bs + (wn * 64 + ni * 16 + col_l) * 64
                                           + (((kk * 4 + quad) ^ swz) * 8));
                b_frag[ni] = __builtin_bit_cast(bf16x8, bv);
            }
#pragma unroll
            for (int mi = 0; mi < 4; ++mi)
#pragma unroll
                for (int ni = 0; ni < 4; ++ni)
                    acc[mi][ni] = __builtin_amdgcn_mfma_f32_16x16x32_bf16(
                        a_frag[mi], b_frag[ni], acc[mi][ni], 0, 0, 0);
        }
        __syncthreads();
    }

#pragma unroll
    for (int ni = 0; ni < 4; ++ni) {
        int col = n0 + wn * 64 + ni * 16 + col_l;
        float bv = bout[col];
#pragma unroll
        for (int mi = 0; mi < 4; ++mi) {
#pragma unroll
            for (int r = 0; r < 4; ++r) {
                int row = m0 + wm * 64 + mi * 16 + quad * 4 + r;
                out[(size_t)row * V_DIM + col] = acc[mi][ni][r] + bv;
            }
        }
    }
}

// ---------- row softmax, in place on d_out ----------
__global__ __launch_bounds__(256) void softmax_rows(float* __restrict__ out) {
    float4* p = (float4*)(out + (size_t)blockIdx.x * V_DIM);
    int tid = threadIdx.x;
    int w = tid >> 6, lane = tid & 63;
    float4 v[4];
    float mx = -3.4e38f;
#pragma unroll
    for (int i = 0; i < 4; ++i) {
        v[i] = p[tid + i * 256];
        mx = fmaxf(mx, fmaxf(fmaxf(v[i].x, v[i].y), fmaxf(v[i].z, v[i].w)));
    }
#pragma unroll
    for (int off = 32; off > 0; off >>= 1) mx = fmaxf(mx, __shfl_xor(mx, off));
    __shared__ float red[4];
    __shared__ float red2[4];
    if (lane == 0) red[w] = mx;
    __syncthreads();
    mx = fmaxf(fmaxf(red[0], red[1]), fmaxf(red[2], red[3]));
    float s = 0.f;
#pragma unroll
    for (int i = 0; i < 4; ++i) {
        v[i].x = __expf(v[i].x - mx); v[i].y = __expf(v[i].y - mx);
        v[i].z = __expf(v[i].z - mx); v[i].w = __expf(v[i].w - mx);
        s += v[i].x + v[i].y + v[i].z + v[i].w;
    }
#pragma unroll
    for (int off = 32; off > 0; off >>= 1) s += __shfl_xor(s, off);
    if (lane == 0) red2[w] = s;
    __syncthreads();
    s = red2[0] + red2[1] + red2[2] + red2[3];
    float inv = 1.0f / s;
#pragma unroll
    for (int i = 0; i < 4; ++i) {
        v[i].x *= inv; v[i].y *= inv; v[i].z *= inv; v[i].w *= inv;
        p[tid + i * 256] = v[i];
    }
}

// ---------- launch ----------
extern "C" void kernel_launch(void* const* d_in, const int* in_sizes, int n_in,
                              void* d_out, int out_size, void* d_ws, size_t ws_size,
                              hipStream_t stream) {
    const float* x    = (const float*)d_in[0];
    const float* h    = (const float*)d_in[1];
    const float* c    = (const float*)d_in[2];
    const float* Wf   = (const float*)d_in[3];
    const float* bf_  = (const float*)d_in[4];
    const float* Wi   = (const float*)d_in[5];
    const float* bi   = (const float*)d_in[6];
    const float* Wc   = (const float*)d_in[7];
    const float* bc   = (const float*)d_in[8];
    const float* Wo   = (const float*)d_in[9];
    const float* bo   = (const float*)d_in[10];
    const float* Wout = (const float*)d_in[11];
    const float* bout = (const float*)d_in[12];

    const size_t XH_ELEMS = (size_t)B_DIM * KX;        // 33,554,432
    const size_t W_ELEMS  = (size_t)H_DIM * KX;        // 33,554,432 per gate
    const size_t HH_ELEMS = (size_t)B_DIM * H_DIM;     // 16,777,216

    // ws layout (bf16/u16 elements): xh | Wg[4] | WoutB | hnew  = 384 MiB total
    u16* xh    = (u16*)d_ws;
    u16* Wg    = xh + XH_ELEMS;
    u16* WoutB = Wg + 4 * W_ELEMS;
    u16* hnew  = WoutB + HH_ELEMS;
    size_t needed = (XH_ELEMS + 4 * W_ELEMS + 2 * HH_ELEMS) * sizeof(u16);
    if (ws_size < needed) return;   // workspace too small: bail rather than corrupt

    float* logits = (float*)d_out;

    // conversions (fp32 -> bf16)
    build_xh<<<(int)(XH_ELEMS / 4 / 256), 256, 0, stream>>>(x, h, xh);
    int w4 = (int)(W_ELEMS / 4);
    cvt_f32_bf16<<<w4 / 256, 256, 0, stream>>>(Wf, Wg + 0 * W_ELEMS, w4);
    cvt_f32_bf16<<<w4 / 256, 256, 0, stream>>>(Wi, Wg + 1 * W_ELEMS, w4);
    cvt_f32_bf16<<<w4 / 256, 256, 0, stream>>>(Wc, Wg + 2 * W_ELEMS, w4);
    cvt_f32_bf16<<<w4 / 256, 256, 0, stream>>>(Wo, Wg + 3 * W_ELEMS, w4);
    int wo4 = (int)(HH_ELEMS / 4);
    cvt_f32_bf16<<<wo4 / 256, 256, 0, stream>>>(Wout, WoutB, wo4);

    // fused 4-gate GEMM + LSTM elementwise -> hnew (bf16)
    gate_gemm<<<dim3(B_DIM / GBM, H_DIM / GBN), 256, 0, stream>>>(
        xh, Wg, bf_, bi, bc, bo, c, hnew);

    // logits = hnew @ Wout^T + bout -> d_out (fp32)
    out_gemm<<<dim3(B_DIM / 128, V_DIM / 128), 256, 0, stream>>>(
        hnew, WoutB, bout, logits);

    // softmax rows in place
    softmax_rows<<<B_DIM, 256, 0, stream>>>(logits);
}